// Round 1
// baseline (1073.618 us; speedup 1.0000x reference)
//
#include <hip/hip_runtime.h>

// Sinkhorn matching loss: B=16,T=64,N=256,D=128; 1024 frames.
// One block per frame, 1024 threads; thread (tr,tc) owns K rows {tr+32i},
// cols {tc+32j} as an 8x8 register tile (strided ownership -> conflict-free
// LDS patterns and intra-wave butterflies for both matvec directions).

constexpr int N = 256;
constexpr int D = 128;
constexpr int NITER = 10;
#define TAUF 0.05f
#define EPSF 1e-8f
#define MUF  (1.0f / 256.0f)

constexpr int CH = 16;            // d-chunk
constexpr int NCH = D / CH;       // 8 chunks
constexpr int SROW = CH + 4;      // 20-float padded row (80B, 16B-aligned)

constexpr int SM_GEMM = 2 * N * SROW;        // 10240 floats (Ss+Ts)
constexpr int SM_IT = 16 * N + N + 64;       // red[16][256] + v[256] + wsum
constexpr int SM_FLOATS = SM_GEMM > SM_IT ? SM_GEMM : SM_IT;

__global__ __launch_bounds__(1024, 4)
void sinkhorn_kernel(const float* __restrict__ Sg, const float* __restrict__ Tg,
                     float* __restrict__ out)
{
    __shared__ float sm[SM_FLOATS];
    __shared__ float s2[N];
    __shared__ float t2[N];

    float (*Ss)[SROW] = (float (*)[SROW])sm;
    float (*Ts)[SROW] = (float (*)[SROW])(sm + N * SROW);
    float (*red)[N]   = (float (*)[N])sm;        // aliases Ss (GEMM phase done)
    float *shv        = sm + 16 * N;             // v[256]
    float *wsum       = sm + 17 * N;             // per-wave partial sums

    const int tid  = threadIdx.x;
    const int tr   = tid >> 5;    // 0..31 row group
    const int tc   = tid & 31;    // 0..31 col group
    const int lane = tid & 63;
    const int wav  = tid >> 6;    // 0..15
    const int f    = blockIdx.x;

    const float4* Sv = (const float4*)(Sg + (size_t)f * N * D);
    const float4* Tv = (const float4*)(Tg + (size_t)f * N * D);

    const int ln = tid >> 2;      // loader row 0..255
    const int lq = tid & 3;       // loader float4 slot 0..3

    float acc[8][8];
#pragma unroll
    for (int i = 0; i < 8; ++i)
#pragma unroll
        for (int j = 0; j < 8; ++j) acc[i][j] = 0.f;

    float sqS = 0.f, sqT = 0.f;

    // ---- GEMM: inner[n][m] = sum_d S[n][d]*T[m][d], chunked over d ----
    for (int c = 0; c < NCH; ++c) {
        // issue global loads for this chunk before the barrier (overlap w/ prev compute)
        float4 a = Sv[ln * 32 + c * 4 + lq];
        float4 b = Tv[ln * 32 + c * 4 + lq];
        __syncthreads();                       // prev chunk's compute done
        *(float4*)&Ss[ln][lq * 4] = a;
        *(float4*)&Ts[ln][lq * 4] = b;
        sqS += a.x * a.x + a.y * a.y + a.z * a.z + a.w * a.w;
        sqT += b.x * b.x + b.y * b.y + b.z * b.z + b.w * b.w;
        __syncthreads();
#pragma unroll
        for (int dd = 0; dd < CH; dd += 4) {
            float4 sv[8];
#pragma unroll
            for (int i = 0; i < 8; ++i)
                sv[i] = *(const float4*)&Ss[tr + 32 * i][dd];
#pragma unroll
            for (int j = 0; j < 8; ++j) {
                float4 tv = *(const float4*)&Ts[tc + 32 * j][dd];
#pragma unroll
                for (int i = 0; i < 8; ++i) {
                    acc[i][j] += sv[i].x * tv.x;
                    acc[i][j] += sv[i].y * tv.y;
                    acc[i][j] += sv[i].z * tv.z;
                    acc[i][j] += sv[i].w * tv.w;
                }
            }
        }
    }

    // squared norms: reduce over the 4 loader lanes of each row
    sqS += __shfl_xor(sqS, 1); sqS += __shfl_xor(sqS, 2);
    sqT += __shfl_xor(sqT, 1); sqT += __shfl_xor(sqT, 2);
    if (lq == 0) { s2[ln] = sqS; t2[ln] = sqT; }
    __syncthreads();              // Ss/Ts now dead; s2/t2 ready

    if (tid < N) shv[tid] = 1.0f; // v init (red region aliases old staging; ok)

    // ---- K = exp(-cost/tau) in registers ----
    {
        float s2r[8], t2c[8];
#pragma unroll
        for (int i = 0; i < 8; ++i) s2r[i] = s2[tr + 32 * i];
#pragma unroll
        for (int j = 0; j < 8; ++j) t2c[j] = t2[tc + 32 * j];
#pragma unroll
        for (int i = 0; i < 8; ++i)
#pragma unroll
            for (int j = 0; j < 8; ++j) {
                float dsq = s2r[i] + t2c[j] - 2.f * acc[i][j];
                float cst = sqrtf(fmaxf(dsq, 0.f));
                acc[i][j] = __expf(cst * (-1.f / TAUF));
            }
    }

    // ---- Sinkhorn iterations ----
    float u[8] = {0.f, 0.f, 0.f, 0.f, 0.f, 0.f, 0.f, 0.f};
    for (int it = 0; it < NITER; ++it) {
        __syncthreads();          // shv ready
        float vr[8];
#pragma unroll
        for (int j = 0; j < 8; ++j) vr[j] = shv[tc + 32 * j];
        // u-step: row sums of K*v
        float rp[8];
#pragma unroll
        for (int i = 0; i < 8; ++i) {
            float s = 0.f;
#pragma unroll
            for (int j = 0; j < 8; ++j) s += acc[i][j] * vr[j];
            rp[i] = s;
        }
#pragma unroll
        for (int m = 1; m <= 16; m <<= 1) {
#pragma unroll
            for (int i = 0; i < 8; ++i) rp[i] += __shfl_xor(rp[i], m);
        }
#pragma unroll
        for (int i = 0; i < 8; ++i) u[i] = MUF / (rp[i] + EPSF);

        // v-step: col sums of K^T*u
        float cp[8];
#pragma unroll
        for (int j = 0; j < 8; ++j) {
            float s = 0.f;
#pragma unroll
            for (int i = 0; i < 8; ++i) s += acc[i][j] * u[i];
            cp[j] = s;
        }
#pragma unroll
        for (int j = 0; j < 8; ++j) cp[j] += __shfl_xor(cp[j], 32);
        if ((tr & 1) == 0) {
#pragma unroll
            for (int j = 0; j < 8; ++j) red[wav][tc + 32 * j] = cp[j];
        }
        __syncthreads();
        if (tid < N) {
            float s = 0.f;
#pragma unroll
            for (int w = 0; w < 16; ++w) s += red[w][tid];
            shv[tid] = MUF / (s + EPSF);
        }
    }
    __syncthreads();

    // ---- final: sum u_n K_nm v_m cost_nm ; cost = -tau*log(K) ----
    float vr[8];
#pragma unroll
    for (int j = 0; j < 8; ++j) vr[j] = shv[tc + 32 * j];
    float fsum = 0.f;
#pragma unroll
    for (int i = 0; i < 8; ++i)
#pragma unroll
        for (int j = 0; j < 8; ++j) {
            float K = acc[i][j];
            float cst = -TAUF * __logf(K);
            fsum += u[i] * K * vr[j] * cst;
        }
#pragma unroll
    for (int m = 1; m <= 32; m <<= 1) fsum += __shfl_xor(fsum, m);
    if (lane == 0) wsum[wav] = fsum;
    __syncthreads();
    if (tid == 0) {
        float s = 0.f;
#pragma unroll
        for (int w = 0; w < 16; ++w) s += wsum[w];
        atomicAdd(out, s * (1.0f / 1024.0f));
    }
}

extern "C" void kernel_launch(void* const* d_in, const int* in_sizes, int n_in,
                              void* d_out, int out_size, void* d_ws, size_t ws_size,
                              hipStream_t stream) {
    const float* S = (const float*)d_in[0];
    const float* T = (const float*)d_in[1];
    float* out = (float*)d_out;
    hipMemsetAsync(out, 0, sizeof(float), stream);
    sinkhorn_kernel<<<dim3(1024), dim3(1024), 0, stream>>>(S, T, out);
}

// Round 2
// 571.216 us; speedup vs baseline: 1.8795x; 1.8795x over previous
//
#include <hip/hip_runtime.h>

// Sinkhorn matching loss: B=16,T=64,N=256,D=128; 1024 frames.
// One block per frame, 1024 threads; thread (tr,tc) owns K rows {tr+32i},
// cols {tc+32j} as an 8x8 register tile. K stays in VGPRs end-to-end.
// Register budget is the whole game: 64 acc + 32 tv + 4 sv + addr < 128
// (hard cap for 16-wave blocks). sv reads are per-tr broadcasts (~free).

constexpr int N = 256;
constexpr int D = 128;
constexpr int NITER = 10;
#define TAUF 0.05f
#define EPSF 1e-8f
#define MUF  (1.0f / 256.0f)

constexpr int CH = 16;            // d-chunk
constexpr int NCH = D / CH;       // 8 chunks
constexpr int SROW = CH + 4;      // 20-float padded row (80B, 16B-aligned)

constexpr int SM_GEMM = 2 * N * SROW;        // 10240 floats (Ss+Ts)
constexpr int SM_IT = 16 * N + N + 64;       // red[16][256] + v[256] + wsum
constexpr int SM_FLOATS = SM_GEMM > SM_IT ? SM_GEMM : SM_IT;

__global__ __launch_bounds__(1024) __attribute__((amdgpu_waves_per_eu(4, 4)))
void sinkhorn_kernel(const float* __restrict__ Sg, const float* __restrict__ Tg,
                     float* __restrict__ out)
{
    __shared__ float sm[SM_FLOATS];
    __shared__ float s2[N];
    __shared__ float t2[N];

    float (*Ss)[SROW] = (float (*)[SROW])sm;
    float (*Ts)[SROW] = (float (*)[SROW])(sm + N * SROW);
    float (*red)[N]   = (float (*)[N])sm;        // aliases Ss (GEMM phase done)
    float *shv        = sm + 16 * N;             // v[256]
    float *wsum       = sm + 17 * N;             // per-wave partial sums

    const int tid  = threadIdx.x;
    const int tr   = tid >> 5;    // 0..31 row group
    const int tc   = tid & 31;    // 0..31 col group
    const int lane = tid & 63;
    const int wav  = tid >> 6;    // 0..15
    const int f    = blockIdx.x;

    const float4* Sv = (const float4*)(Sg + (size_t)f * N * D);
    const float4* Tv = (const float4*)(Tg + (size_t)f * N * D);

    const int ln = tid >> 2;      // loader row 0..255
    const int lq = tid & 3;       // loader float4 slot 0..3

    float acc[8][8];
#pragma unroll
    for (int i = 0; i < 8; ++i)
#pragma unroll
        for (int j = 0; j < 8; ++j) acc[i][j] = 0.f;

    float sqS = 0.f, sqT = 0.f;

    // ---- GEMM: inner[n][m] = sum_d S[n][d]*T[m][d], chunked over d ----
#pragma unroll 1
    for (int c = 0; c < NCH; ++c) {
        // issue global loads before the barrier (overlap w/ prev chunk compute)
        float4 a = Sv[ln * 32 + c * 4 + lq];
        float4 b = Tv[ln * 32 + c * 4 + lq];
        __syncthreads();                       // prev chunk's compute done
        *(float4*)&Ss[ln][lq * 4] = a;
        *(float4*)&Ts[ln][lq * 4] = b;
        sqS += a.x * a.x + a.y * a.y + a.z * a.z + a.w * a.w;
        sqT += b.x * b.x + b.y * b.y + b.z * b.z + b.w * b.w;
        __syncthreads();
#pragma unroll 1
        for (int dd = 0; dd < CH; dd += 4) {
            float4 tv[8];
#pragma unroll
            for (int j = 0; j < 8; ++j)
                tv[j] = *(const float4*)&Ts[tc + 32 * j][dd];
#pragma unroll
            for (int i = 0; i < 8; ++i) {
                // broadcast read: address depends only on tr (2 addrs/wave)
                float4 s = *(const float4*)&Ss[tr + 32 * i][dd];
#pragma unroll
                for (int j = 0; j < 8; ++j) {
                    acc[i][j] = fmaf(s.x, tv[j].x, acc[i][j]);
                    acc[i][j] = fmaf(s.y, tv[j].y, acc[i][j]);
                    acc[i][j] = fmaf(s.z, tv[j].z, acc[i][j]);
                    acc[i][j] = fmaf(s.w, tv[j].w, acc[i][j]);
                }
            }
        }
    }

    // squared norms: reduce over the 4 loader lanes of each row
    sqS += __shfl_xor(sqS, 1); sqS += __shfl_xor(sqS, 2);
    sqT += __shfl_xor(sqT, 1); sqT += __shfl_xor(sqT, 2);
    if (lq == 0) { s2[ln] = sqS; t2[ln] = sqT; }
    __syncthreads();              // Ss/Ts now dead; s2/t2 ready

    if (tid < N) shv[tid] = 1.0f; // v init (red region aliases old staging; ok)

    // ---- K = exp(-cost/tau) in registers ----
    {
        float s2r[8], t2c[8];
#pragma unroll
        for (int i = 0; i < 8; ++i) s2r[i] = s2[tr + 32 * i];
#pragma unroll
        for (int j = 0; j < 8; ++j) t2c[j] = t2[tc + 32 * j];
#pragma unroll
        for (int i = 0; i < 8; ++i)
#pragma unroll
            for (int j = 0; j < 8; ++j) {
                float dsq = s2r[i] + t2c[j] - 2.f * acc[i][j];
                float cst = sqrtf(fmaxf(dsq, 0.f));
                acc[i][j] = __expf(cst * (-1.f / TAUF));
            }
    }

    // ---- Sinkhorn iterations ----
    float u[8] = {0.f, 0.f, 0.f, 0.f, 0.f, 0.f, 0.f, 0.f};
#pragma unroll 1
    for (int it = 0; it < NITER; ++it) {
        __syncthreads();          // shv ready
        float vr[8];
#pragma unroll
        for (int j = 0; j < 8; ++j) vr[j] = shv[tc + 32 * j];
        // u-step: row sums of K*v
        float rp[8];
#pragma unroll
        for (int i = 0; i < 8; ++i) {
            float s = 0.f;
#pragma unroll
            for (int j = 0; j < 8; ++j) s += acc[i][j] * vr[j];
            rp[i] = s;
        }
#pragma unroll
        for (int m = 1; m <= 16; m <<= 1) {
#pragma unroll
            for (int i = 0; i < 8; ++i) rp[i] += __shfl_xor(rp[i], m);
        }
#pragma unroll
        for (int i = 0; i < 8; ++i) u[i] = MUF / (rp[i] + EPSF);

        // v-step: col sums of K^T*u
        float cp[8];
#pragma unroll
        for (int j = 0; j < 8; ++j) {
            float s = 0.f;
#pragma unroll
            for (int i = 0; i < 8; ++i) s += acc[i][j] * u[i];
            cp[j] = s;
        }
#pragma unroll
        for (int j = 0; j < 8; ++j) cp[j] += __shfl_xor(cp[j], 32);
        if ((tr & 1) == 0) {
#pragma unroll
            for (int j = 0; j < 8; ++j) red[wav][tc + 32 * j] = cp[j];
        }
        __syncthreads();
        if (tid < N) {
            float s = 0.f;
#pragma unroll
            for (int w = 0; w < 16; ++w) s += red[w][tid];
            shv[tid] = MUF / (s + EPSF);
        }
    }
    __syncthreads();

    // ---- final: sum u_n K_nm v_m cost_nm ; cost = -tau*log(K) ----
    float vr[8];
#pragma unroll
    for (int j = 0; j < 8; ++j) vr[j] = shv[tc + 32 * j];
    float fsum = 0.f;
#pragma unroll
    for (int i = 0; i < 8; ++i)
#pragma unroll
        for (int j = 0; j < 8; ++j) {
            float K = acc[i][j];
            float cst = -TAUF * __logf(K);
            fsum += u[i] * K * vr[j] * cst;
        }
#pragma unroll
    for (int m = 1; m <= 32; m <<= 1) fsum += __shfl_xor(fsum, m);
    if (lane == 0) wsum[wav] = fsum;
    __syncthreads();
    if (tid == 0) {
        float s = 0.f;
#pragma unroll
        for (int w = 0; w < 16; ++w) s += wsum[w];
        atomicAdd(out, s * (1.0f / 1024.0f));
    }
}

extern "C" void kernel_launch(void* const* d_in, const int* in_sizes, int n_in,
                              void* d_out, int out_size, void* d_ws, size_t ws_size,
                              hipStream_t stream) {
    const float* S = (const float*)d_in[0];
    const float* T = (const float*)d_in[1];
    float* out = (float*)d_out;
    hipMemsetAsync(out, 0, sizeof(float), stream);
    sinkhorn_kernel<<<dim3(1024), dim3(1024), 0, stream>>>(S, T, out);
}